// Round 4
// baseline (230.387 us; speedup 1.0000x reference)
//
#include <hip/hip_runtime.h>

#define LAMBDA_COORD 5.0f
#define LAMBDA_NOOBJ 0.5f
#define DD 30
#define BLOCK 128                  // 2 waves
#define CPB 128                    // cells per block-tile
#define TILE_FLOATS (CPB * DD)     // 3840 floats = 15360 B per input
// combined tile = P(960 chunks) + T(960 chunks) of 16B = 1920 chunks = 15/thread

// element k of a float2[15] register array (k compile-time after unroll)
#define EL(A, k) (((k) & 1) ? A[(k) >> 1].y : A[(k) >> 1].x)

__device__ __forceinline__ float iou_t(float tx, float ty, float tw, float th,
                                       float px, float py, float pw, float ph) {
    float xl = fmaxf(tx - tw * 0.5f, px - pw * 0.5f);
    float yt = fmaxf(ty - th * 0.5f, py - ph * 0.5f);
    float xr = fminf(tx + tw * 0.5f, px + pw * 0.5f);
    float yb = fminf(ty + th * 0.5f, py + ph * 0.5f);
    bool valid = (xr >= xl) && (yb >= yt);
    float inter = (xr - xl) * (yb - yt);
    float uni = tw * th + pw * ph - inter;
    float safe = (uni == 0.0f) ? 1.0f : uni;
    return valid ? (inter / safe) : 0.0f;
}

__global__ __launch_bounds__(BLOCK) void yolo_loss_kernel(
    const float* __restrict__ pred, const float* __restrict__ targ,
    float* __restrict__ out) {
    // single 30720B staged tile (P then T) -> 5 blocks/CU, 10 waves/CU.
    // TLP across 5 independent blocks hides the load->write->barrier drain
    // (m219/m238 pattern: no explicit pipelining at high occupancy).
    __shared__ __align__(16) float lds[2 * TILE_FLOATS];
    __shared__ float wpart[BLOCK / 64];

    const int tid = threadIdx.x;

    const float* bp = pred + (size_t)blockIdx.x * TILE_FLOATS;
    const float* bt = targ + (size_t)blockIdx.x * TILE_FLOATS;

    // ---- coalesced global -> register staging (register path, full MLP) ----
    // chunk idx = c*128 + tid in [0,1920): [0,960) = P tile, [960,1920) = T.
    // Per wave per c the predicate is uniform; wave reads 1KB contiguous.
    float4 v[15];
#pragma unroll
    for (int c = 0; c < 15; ++c) {
        int idx = c * BLOCK + tid;
        const float* src = (idx < 960) ? (bp + (size_t)idx * 4)
                                       : (bt + (size_t)(idx - 960) * 4);
        v[c] = *(const float4*)src;
    }
    // ---- register -> LDS (linear ds_write_b128, conflict-free) ----
#pragma unroll
    for (int c = 0; c < 15; ++c) {
        int idx = c * BLOCK + tid;
        *(float4*)(lds + (size_t)idx * 4) = v[c];
    }
    __syncthreads();

    // ---- per-cell loss from LDS (float2 = ds_read_b64) ----
    const float2* lp = (const float2*)lds + tid * (DD / 2);
    const float2* lt = (const float2*)(lds + TILE_FLOATS) + tid * (DD / 2);

    float2 P[15], T[15];
#pragma unroll
    for (int j = 0; j < 15; ++j) P[j] = lp[j];
#pragma unroll
    for (int j = 0; j < 15; ++j) {
        if (j == 3 || j == 4) continue;    // target floats 6..9 unused
        T[j] = lt[j];
    }

    float t4 = EL(T, 4);
    float obj = (t4 > 0.0f) ? 1.0f : 0.0f;
    float noobj = (t4 == 0.0f) ? 1.0f : 0.0f;

    float cls = 0.0f;
#pragma unroll
    for (int j = 5; j < 15; ++j) {         // channels 10..29
        float dx = T[j].x - P[j].x;
        float dy = T[j].y - P[j].y;
        cls += dx * dx + dy * dy;
    }
    cls *= obj;

    float d4 = t4 - EL(P, 4);
    float conf_noobj = noobj * d4 * d4;

    float tx = EL(T, 0), ty = EL(T, 1), tw = EL(T, 2), th = EL(T, 3);
    float p0 = EL(P, 0), p1 = EL(P, 1), p2 = EL(P, 2), p3 = EL(P, 3);
    float p4 = EL(P, 4), p5 = EL(P, 5), p6 = EL(P, 6), p7 = EL(P, 7);
    float p8 = EL(P, 8), p9 = EL(P, 9);

    float iou1 = iou_t(tx, ty, tw, th, p0, p1, p2, p3);
    float iou2 = iou_t(tx, ty, tw, th, p5, p6, p7, p8);
    float resp1 = (iou1 > iou2) ? 1.0f : 0.0f;
    float m1 = obj * resp1;
    float m2 = obj * (1.0f - resp1);

    float e1 = iou1 - p4;
    float e2 = iou2 - p9;
    float conf_obj = m1 * e1 * e1 + m2 * e2 * e2;

    float dx1 = tx - p0, dy1 = ty - p1;
    float dx2 = tx - p5, dy2 = ty - p6;
    float xy = m1 * (dx1 * dx1 + dy1 * dy1) + m2 * (dx2 * dx2 + dy2 * dy2);

    float dw1 = tw - p2, dh1 = th - p3;
    float dw2 = tw - p7, dh2 = th - p8;
    float wh = m1 * (dw1 * dw1 + dh1 * dh1) + m2 * (dw2 * dw2 + dh2 * dh2);

    float loss = LAMBDA_COORD * (xy + wh) + conf_obj + LAMBDA_NOOBJ * conf_noobj + cls;

    // ---- 64-lane wave reduction, then block reduction, one atomic/block ----
#pragma unroll
    for (int off = 32; off > 0; off >>= 1) loss += __shfl_down(loss, off);
    if ((tid & 63) == 0) wpart[tid >> 6] = loss;
    __syncthreads();
    if (tid == 0) {
        atomicAdd(out, (wpart[0] + wpart[1]) * (1.0f / 16384.0f));
    }
}

extern "C" void kernel_launch(void* const* d_in, const int* in_sizes, int n_in,
                              void* d_out, int out_size, void* d_ws, size_t ws_size,
                              hipStream_t stream) {
    const float* pred = (const float*)d_in[0];  // y
    const float* targ = (const float*)d_in[1];  // gt
    float* out = (float*)d_out;

    hipMemsetAsync(out, 0, sizeof(float), stream);

    const int cells = in_sizes[0] / DD;   // 802816
    const int grid = cells / CPB;         // 6272 (exact)
    yolo_loss_kernel<<<grid, BLOCK, 0, stream>>>(pred, targ, out);
}

// Round 6
// 226.564 us; speedup vs baseline: 1.0169x; 1.0169x over previous
//
#include <hip/hip_runtime.h>

#define LAMBDA_COORD 5.0f
#define LAMBDA_NOOBJ 0.5f
#define DD 30
#define BLOCK 256
#define CPB 256                     // cells per block (1 cell per thread for box phase)
#define TILE_F (CPB * DD)           // 7680 floats per array per block
#define TILE_C4 (TILE_F / 4)        // 1920 float4 chunks per array

__device__ __forceinline__ float iou_t(float tx, float ty, float tw, float th,
                                       float px, float py, float pw, float ph) {
    float xl = fmaxf(tx - tw * 0.5f, px - pw * 0.5f);
    float yt = fmaxf(ty - th * 0.5f, py - ph * 0.5f);
    float xr = fminf(tx + tw * 0.5f, px + pw * 0.5f);
    float yb = fminf(ty + th * 0.5f, py + ph * 0.5f);
    bool valid = (xr >= xl) && (yb >= yt);
    float inter = (xr - xl) * (yb - yt);
    float uni = tw * th + pw * ph - inter;
    float safe = (uni == 0.0f) ? 1.0f : uni;
    return valid ? (inter / safe) : 0.0f;
}

// Occupancy is the lever: only 2KB LDS, force 8 waves/SIMD (32/CU).
__global__ __launch_bounds__(BLOCK, 8) void yolo_loss_kernel(
    const float* __restrict__ pred, const float* __restrict__ targ,
    float* __restrict__ out) {
    __shared__ float objL[CPB];     // obj mask per cell
    __shared__ float noobjL[CPB];   // 0.5 * noobj per cell (pre-scaled)
    __shared__ float wpart[BLOCK / 64];

    const int tid = threadIdx.x;
    const size_t base = (size_t)blockIdx.x * TILE_F;
    const float* bp = pred + base;
    const float* bt = targ + base;

    float acc = 0.0f;

    // ---- phase 1: per-thread cell -> box terms (strided dwordx2, 8/thread) ----
    {
        const float2* rp = (const float2*)(bp + tid * DD);
        const float2* rt = (const float2*)(bt + tid * DD);
        float2 p01 = rp[0], p23 = rp[1], p45 = rp[2], p67 = rp[3], p89 = rp[4];
        float2 t01 = rt[0], t23 = rt[1], t45 = rt[2];

        float t4 = t45.x;
        float obj = (t4 > 0.0f) ? 1.0f : 0.0f;
        float noobj = (t4 == 0.0f) ? 1.0f : 0.0f;
        objL[tid] = obj;
        noobjL[tid] = LAMBDA_NOOBJ * noobj;   // conf_noobj handled in phase 2

        float tx = t01.x, ty = t01.y, tw = t23.x, th = t23.y;
        // pred box1 = ch0..3, conf1 = ch4; box2 = ch5..8, conf2 = ch9
        float iou1 = iou_t(tx, ty, tw, th, p01.x, p01.y, p23.x, p23.y);
        float iou2 = iou_t(tx, ty, tw, th, p45.y, p67.x, p67.y, p89.x);
        float resp1 = (iou1 > iou2) ? 1.0f : 0.0f;
        float m1 = obj * resp1;
        float m2 = obj * (1.0f - resp1);

        float e1 = iou1 - p45.x;   // - p4
        float e2 = iou2 - p89.y;   // - p9
        float conf_obj = m1 * e1 * e1 + m2 * e2 * e2;

        float dx1 = tx - p01.x, dy1 = ty - p01.y;
        float dx2 = tx - p45.y, dy2 = ty - p67.x;
        float xy = m1 * (dx1 * dx1 + dy1 * dy1) + m2 * (dx2 * dx2 + dy2 * dy2);

        float dw1 = tw - p23.x, dh1 = th - p23.y;
        float dw2 = tw - p67.y, dh2 = th - p89.x;
        float wh = m1 * (dw1 * dw1 + dh1 * dh1) + m2 * (dw2 * dw2 + dh2 * dh2);

        acc += LAMBDA_COORD * (xy + wh) + conf_obj;
    }
    __syncthreads();

    // ---- phase 2: fully-coalesced elementwise stream (m13 pattern) ----
    // cls (ch>=10): obj * (t-p)^2 ; conf_noobj (ch==4): 0.5*noobj*(t-p)^2
    const float4* cp = (const float4*)bp;
    const float4* ct = (const float4*)bt;
#pragma unroll
    for (int c = 0; c < 8; ++c) {
        int idx = c * BLOCK + tid;
        if (idx < TILE_C4) {               // last iter: waves 0,1 only (uniform)
            float4 p = cp[idx];
            float4 t = ct[idx];
            float pe[4] = {p.x, p.y, p.z, p.w};
            float te[4] = {t.x, t.y, t.z, t.w};
            int f0 = idx * 4;
#pragma unroll
            for (int e = 0; e < 4; ++e) {
                int fe = f0 + e;
                int cell = fe / 30;        // magic-mul, CSE'd by compiler
                int ch = fe - cell * 30;
                float d = te[e] - pe[e];
                float w = (ch >= 10) ? objL[cell]
                         : ((ch == 4) ? noobjL[cell] : 0.0f);
                acc += w * d * d;
            }
        }
    }

    // ---- 64-lane wave reduction, block reduction, one atomic/block ----
#pragma unroll
    for (int off = 32; off > 0; off >>= 1) acc += __shfl_down(acc, off);
    if ((tid & 63) == 0) wpart[tid >> 6] = acc;
    __syncthreads();
    if (tid == 0) {
        atomicAdd(out, (wpart[0] + wpart[1] + wpart[2] + wpart[3]) *
                           (1.0f / 16384.0f));
    }
}

extern "C" void kernel_launch(void* const* d_in, const int* in_sizes, int n_in,
                              void* d_out, int out_size, void* d_ws, size_t ws_size,
                              hipStream_t stream) {
    const float* pred = (const float*)d_in[0];  // y
    const float* targ = (const float*)d_in[1];  // gt
    float* out = (float*)d_out;

    hipMemsetAsync(out, 0, sizeof(float), stream);

    const int cells = in_sizes[0] / DD;   // 802816
    const int grid = cells / CPB;         // 3136 (exact)
    yolo_loss_kernel<<<grid, BLOCK, 0, stream>>>(pred, targ, out);
}

// Round 8
// 206.400 us; speedup vs baseline: 1.1162x; 1.0977x over previous
//
#include <hip/hip_runtime.h>

#define LAMBDA_COORD 5.0f
#define LAMBDA_NOOBJ 0.5f
#define DD 30
#define BLOCK 256
#define NPART 3136   // kernel-1 grid = cells / BLOCK

// element k of a float2[15] register array (k compile-time after unroll)
#define EL(A, k) (((k) & 1) ? A[(k) >> 1].y : A[(k) >> 1].x)

__device__ __forceinline__ float iou_t(float tx, float ty, float tw, float th,
                                       float px, float py, float pw, float ph) {
    float xl = fmaxf(tx - tw * 0.5f, px - pw * 0.5f);
    float yt = fmaxf(ty - th * 0.5f, py - ph * 0.5f);
    float xr = fminf(tx + tw * 0.5f, px + pw * 0.5f);
    float yb = fminf(ty + th * 0.5f, py + ph * 0.5f);
    bool valid = (xr >= xl) && (yb >= yt);
    float inter = (xr - xl) * (yb - yt);
    float uni = tw * th + pw * ph - inter;
    float safe = (uni == 0.0f) ? 1.0f : uni;
    return valid ? (inter / safe) : 0.0f;
}

// Stage 1: identical per-cell math + per-block reduction to the 205.5us
// session-verified baseline; only the tail changes (deterministic partial
// store instead of float atomicAdd — the atomic's cross-run reorder noise
// tripped the post-timing determinism check in round 7).
__global__ __launch_bounds__(BLOCK, 4) void yolo_loss_partial(
    const float* __restrict__ pred, const float* __restrict__ targ,
    float* __restrict__ part) {
    __shared__ float wpart[BLOCK / 64];

    const int tid = threadIdx.x;
    const size_t cell = (size_t)blockIdx.x * BLOCK + tid;

    const float2* gp = (const float2*)(pred + cell * DD);
    const float2* gt = (const float2*)(targ + cell * DD);
    float2 P[15], T[15];
#pragma unroll
    for (int j = 0; j < 15; ++j) P[j] = gp[j];
#pragma unroll
    for (int j = 0; j < 15; ++j) T[j] = gt[j];

    float t4 = EL(T, 4);
    float obj = (t4 > 0.0f) ? 1.0f : 0.0f;
    float noobj = (t4 == 0.0f) ? 1.0f : 0.0f;

    float cls = 0.0f;
#pragma unroll
    for (int j = 5; j < 15; ++j) {   // channels 10..29
        float dx = T[j].x - P[j].x;
        float dy = T[j].y - P[j].y;
        cls += dx * dx + dy * dy;
    }
    cls *= obj;

    float d4 = t4 - EL(P, 4);
    float conf_noobj = noobj * d4 * d4;

    float tx = EL(T, 0), ty = EL(T, 1), tw = EL(T, 2), th = EL(T, 3);
    float p0 = EL(P, 0), p1 = EL(P, 1), p2 = EL(P, 2), p3 = EL(P, 3);
    float p4 = EL(P, 4), p5 = EL(P, 5), p6 = EL(P, 6), p7 = EL(P, 7);
    float p8 = EL(P, 8), p9 = EL(P, 9);

    float iou1 = iou_t(tx, ty, tw, th, p0, p1, p2, p3);
    float iou2 = iou_t(tx, ty, tw, th, p5, p6, p7, p8);
    float resp1 = (iou1 > iou2) ? 1.0f : 0.0f;
    float m1 = obj * resp1;
    float m2 = obj * (1.0f - resp1);

    float e1 = iou1 - p4;
    float e2 = iou2 - p9;
    float conf_obj = m1 * e1 * e1 + m2 * e2 * e2;

    float dx1 = tx - p0, dy1 = ty - p1;
    float dx2 = tx - p5, dy2 = ty - p6;
    float xy = m1 * (dx1 * dx1 + dy1 * dy1) + m2 * (dx2 * dx2 + dy2 * dy2);

    float dw1 = tw - p2, dh1 = th - p3;
    float dw2 = tw - p7, dh2 = th - p8;
    float wh = m1 * (dw1 * dw1 + dh1 * dh1) + m2 * (dw2 * dw2 + dh2 * dh2);

    float loss = LAMBDA_COORD * (xy + wh) + conf_obj + LAMBDA_NOOBJ * conf_noobj + cls;

    // 64-lane wave reduction, block reduction -> deterministic partial store
#pragma unroll
    for (int off = 32; off > 0; off >>= 1) loss += __shfl_down(loss, off);
    if ((tid & 63) == 0) wpart[tid >> 6] = loss;
    __syncthreads();
    if (tid == 0)
        part[blockIdx.x] = wpart[0] + wpart[1] + wpart[2] + wpart[3];
}

// Stage 2: one block sums the 3136 partials in DOUBLE with a fixed
// association tree -> bit-stable output across every invocation.
__global__ __launch_bounds__(256, 1) void yolo_loss_final(
    const float* __restrict__ part, float* __restrict__ out) {
    __shared__ double dpart[4];
    const int tid = threadIdx.x;

    double s = 0.0;
    for (int i = tid; i < NPART; i += 256) s += (double)part[i];
#pragma unroll
    for (int off = 32; off > 0; off >>= 1) s += __shfl_down(s, off);
    if ((tid & 63) == 0) dpart[tid >> 6] = s;
    __syncthreads();
    if (tid == 0)
        out[0] = (float)((dpart[0] + dpart[1] + dpart[2] + dpart[3]) *
                         (1.0 / 16384.0));
}

extern "C" void kernel_launch(void* const* d_in, const int* in_sizes, int n_in,
                              void* d_out, int out_size, void* d_ws, size_t ws_size,
                              hipStream_t stream) {
    const float* pred = (const float*)d_in[0];  // y
    const float* targ = (const float*)d_in[1];  // gt
    float* out = (float*)d_out;
    float* part = (float*)d_ws;                 // 3136 floats = 12.5 KB

    const int cells = in_sizes[0] / DD;   // 802816
    const int grid = cells / BLOCK;       // 3136 (exact)
    // No memset: both kernels fully overwrite their outputs every call.
    yolo_loss_partial<<<grid, BLOCK, 0, stream>>>(pred, targ, part);
    yolo_loss_final<<<1, 256, 0, stream>>>(part, out);
}